// Round 16
// baseline (648.580 us; speedup 1.0000x reference)
//
#include <hip/hip_runtime.h>
#include <hip/hip_bf16.h>
#include <hip/hip_fp16.h>

#define NN 50000
#define EE 500000
#define DIN 64
#define HIDD 128
#define NG 64
#define NB1 49  // ceil(NN/1024) scan blocks

typedef short short8 __attribute__((ext_vector_type(8)));
typedef float f32x4 __attribute__((ext_vector_type(4)));
typedef _Float16 hf2 __attribute__((ext_vector_type(2)));

// async global->LDS, 16B per lane; LDS dest = wave-uniform base + lane*16
#define GLL(g, l)                                                              \
  __builtin_amdgcn_global_load_lds(                                            \
      (const __attribute__((address_space(1))) unsigned*)(g),                  \
      (__attribute__((address_space(3))) unsigned*)(l), 16, 0, 0)

__device__ __forceinline__ unsigned short f2bf(float f) {
  unsigned u = __float_as_uint(f);
  u += 0x7fffu + ((u >> 16) & 1u);  // RNE
  return (unsigned short)(u >> 16);
}
__device__ __forceinline__ float bfl(unsigned short u) {
  return __uint_as_float((unsigned)u << 16);
}
__device__ __forceinline__ unsigned short f2h(float f) {
  __half h = __float2half(f);
  return *(unsigned short*)&h;
}
__device__ __forceinline__ hf2 u2h2(unsigned u) {
  union { unsigned u; hf2 h; } c; c.u = u; return c.h;
}
__device__ __forceinline__ float dot2a(hf2 a, hf2 b, float c) {
#if __has_builtin(__builtin_amdgcn_fdot2)
  return __builtin_amdgcn_fdot2(a, b, c, false);
#else
  return c + (float)a.x * (float)b.x + (float)a.y * (float)b.y;
#endif
}

struct BiasW { const float* b[4]; };
struct PrepW { const float* w[12]; };

// ---------------- CSR build ----------------
__global__ __launch_bounds__(256) void count_kernel(const int* __restrict__ ei,
                                                    int* __restrict__ cnt, int E) {
  int e = blockIdx.x * 256 + threadIdx.x;
  if (e < E) atomicAdd(&cnt[ei[E + e]], 1);
}

__global__ __launch_bounds__(1024) void scan1_kernel(const int* __restrict__ cnts,
                                                     int* __restrict__ starts,
                                                     int* __restrict__ btot) {
  __shared__ int sh[1024];
  int t = threadIdx.x;
  int idx = blockIdx.x * 1024 + t;
  int v = (idx < NN) ? cnts[idx] : 0;
  sh[t] = v;
  __syncthreads();
  for (int off = 1; off < 1024; off <<= 1) {
    int add = (t >= off) ? sh[t - off] : 0;
    __syncthreads();
    sh[t] += add;
    __syncthreads();
  }
  if (idx < NN) starts[idx] = sh[t] - v;
  if (t == 1023) btot[blockIdx.x] = sh[1023];
}

__global__ __launch_bounds__(64) void scan2_kernel(const int* __restrict__ btot,
                                                   int* __restrict__ boff,
                                                   int* __restrict__ starts) {
  int t = threadIdx.x;
  int orig = (t < NB1) ? btot[t] : 0;
  int v = orig;
  for (int off = 1; off < 64; off <<= 1) {
    int n_ = __shfl_up(v, off);
    if (t >= off) v += n_;
  }
  if (t < NB1) boff[t] = v - orig;
  if (t == NB1 - 1) starts[NN] = v;
}

__global__ __launch_bounds__(256) void scan3_kernel(int* __restrict__ starts,
                                                    const int* __restrict__ boff,
                                                    int* __restrict__ pos) {
  int i = blockIdx.x * 256 + threadIdx.x;
  if (i < NN) {
    int s = starts[i] + boff[i >> 10];
    starts[i] = s;
    pos[i] = s;
  }
}

__global__ __launch_bounds__(256) void scatter_kernel(const int* __restrict__ ei,
                                                      int* __restrict__ pos,
                                                      int* __restrict__ csr_src, int E) {
  int e = blockIdx.x * 256 + threadIdx.x;
  if (e < 8) csr_src[E + e] = 0;  // zero pad so tail batches can overread safely
  if (e < E) {
    int dst = ei[E + e];
    int p = atomicAdd(&pos[dst], 1);
    csr_src[p] = ei[e];
  }
}

// ---------------- weight prep: transpose + bf16 + PRE-SWIZZLE ----------------
// Stored so a LINEAR global_load_lds copy yields the XOR-swizzled LDS image:
//   LDSbyte[col*RB + (slot*16 ^ ((col&7)<<4)) + 2j] = W[slot*8+j][col]
// mats 0..3 (l0, K=64): at m*8192 shorts; mats 4..11 (K=128): at 32768+(m-4)*16384
__global__ __launch_bounds__(256) void prep_kernel(PrepW pw, short* __restrict__ wT) {
  int o = blockIdx.x * 256 + threadIdx.x;
  if (o >= 163840) return;
  int m, local, K;
  if (o < 32768) { m = o >> 13; local = o & 8191; K = 64; }
  else { int oo = o - 32768; m = 4 + (oo >> 14); local = oo & 16383; K = 128; }
  int col = local / K;
  int off = (local % K) * 2;              // byte offset within col
  int sw = off ^ ((col & 7) << 4);        // un-swizzle (XOR hits bits 4-6 only)
  int k = (sw >> 4) * 8 + ((sw & 15) >> 1);
  wT[o] = (short)f2bf(pw.w[m][(size_t)k * 128 + col]);
}

// ---------------- paired-mat persistent GEMM (512 threads = 8 waves) ----------------
// grid (GX, 2): y=0 computes Q & S, y=1 computes K & V. Both mats' B staged into
// LDS once (2x32KB), then grid-stride over 128-row chunks (8 waves x 16 rows);
// A-fragments loaded once per chunk feed BOTH mats' MFMAs. K&V epilogue emits one
// coalesced 16B uint4 per cf in the interleaved layout attn reads.
template <int K, bool BF16IN>
__global__ __launch_bounds__(512, 4) void gemm_pair(
    const void* __restrict__ hin, const short* __restrict__ wT, BiasW bw,
    unsigned short* __restrict__ qb, unsigned short* __restrict__ kvb,
    unsigned short* __restrict__ sb, int N) {
  constexpr int RB = 2 * K;
  constexpr int CALLS = (128 * RB) / 8192;  // 4 (K=128) or 2 (K=64) per mat
  const float QSC = 0.17677669529663687f;   // 1/sqrt(32)
  __shared__ short bS[2][128 * K];
  const int grp = blockIdx.y;               // 0: Q,S   1: K,V
  const int m0 = grp ? 1 : 0;
  const int m1 = grp ? 2 : 3;
  const int t = threadIdx.x, l = t & 63, wv = t >> 6;  // 8 waves

  {
    const char* g0 = (const char*)(wT + (size_t)m0 * 128 * K);
    const char* g1 = (const char*)(wT + (size_t)m1 * 128 * K);
    char* lp0 = (char*)&bS[0][0];
    char* lp1 = (char*)&bS[1][0];
#pragma unroll
    for (int i = 0; i < CALLS; ++i)
      GLL(g0 + i * 8192 + wv * 1024 + l * 16, lp0 + i * 8192 + wv * 1024);
#pragma unroll
    for (int i = 0; i < CALLS; ++i)
      GLL(g1 + i * 8192 + wv * 1024 + l * 16, lp1 + i * 8192 + wv * 1024);
  }
  __syncthreads();  // both B mats resident for the whole kernel

  const int lr = l & 15, lk = l >> 4;
  const float* __restrict__ bias0 = bw.b[m0];
  const float* __restrict__ bias1 = bw.b[m1];

  for (int r0 = blockIdx.x * 128 + wv * 16; r0 < N; r0 += gridDim.x * 128) {
    const int gr = r0 + lr;     // this lane's node (B-frag row AND output node)
    const bool ok = gr < N;
    short8 hfrag[K / 32];
    if (BF16IN) {
      const short* hs = (const short*)hin;
#pragma unroll
      for (int ks = 0; ks < K / 32; ++ks) {
        short8 z = {0, 0, 0, 0, 0, 0, 0, 0};
        hfrag[ks] = ok ? *(const short8*)(hs + (size_t)gr * K + ks * 32 + lk * 8) : z;
      }
    } else {
      const float* hf = (const float*)hin;
#pragma unroll
      for (int ks = 0; ks < K / 32; ++ks) {
        short8 pk = {0, 0, 0, 0, 0, 0, 0, 0};
        if (ok) {
          const float* hp = hf + (size_t)gr * K + ks * 32 + lk * 8;
          f32x4 f0 = *(const f32x4*)hp;
          f32x4 f1 = *(const f32x4*)(hp + 4);
          pk[0] = f2bf(f0.x); pk[1] = f2bf(f0.y); pk[2] = f2bf(f0.z); pk[3] = f2bf(f0.w);
          pk[4] = f2bf(f1.x); pk[5] = f2bf(f1.y); pk[6] = f2bf(f1.z); pk[7] = f2bf(f1.w);
        }
        hfrag[ks] = pk;
      }
    }

    f32x4 accA[8] = {}, accB[8] = {};
#pragma unroll
    for (int ks = 0; ks < K / 32; ++ks) {
#pragma unroll
      for (int cf = 0; cf < 8; ++cf) {
        int col = cf * 16 + lr;   // W column (channel) = A-frag row
        unsigned bb = col * RB + ((((ks * 4 + lk) * 16)) ^ ((col & 7) << 4));
        short8 w0 = *(const short8*)((const char*)&bS[0][0] + bb);
        short8 w1 = *(const short8*)((const char*)&bS[1][0] + bb);
        accA[cf] = __builtin_amdgcn_mfma_f32_16x16x32_bf16(w0, hfrag[ks], accA[cf], 0, 0, 0);
        accB[cf] = __builtin_amdgcn_mfma_f32_16x16x32_bf16(w1, hfrag[ks], accB[cf], 0, 0, 0);
      }
    }

    if (gr < N) {
#pragma unroll
      for (int cf = 0; cf < 8; ++cf) {
        int ch0 = cf * 16 + lk * 4;   // 4 contiguous channels for this lane
        f32x4 bA = *(const f32x4*)&bias0[ch0];
        f32x4 bB = *(const f32x4*)&bias1[ch0];
        float a0 = accA[cf][0] + bA.x, a1 = accA[cf][1] + bA.y;
        float a2 = accA[cf][2] + bA.z, a3 = accA[cf][3] + bA.w;
        float c0 = accB[cf][0] + bB.x, c1 = accB[cf][1] + bB.y;
        float c2 = accB[cf][2] + bB.z, c3 = accB[cf][3] + bB.w;
        if (grp == 0) {
          ushort4 q;
          q.x = f2h(a0 * QSC); q.y = f2h(a1 * QSC);
          q.z = f2h(a2 * QSC); q.w = f2h(a3 * QSC);
          *(ushort4*)&qb[(size_t)gr * 128 + ch0] = q;
          ushort4 s;
          s.x = f2bf(c0); s.y = f2bf(c1); s.z = f2bf(c2); s.w = f2bf(c3);
          *(ushort4*)&sb[(size_t)gr * 128 + ch0] = s;
        } else {
          uint4 o;
          o.x = (unsigned)f2h(a0) | ((unsigned)f2h(a1) << 16);  // K pair ch0,ch0+1
          o.y = (unsigned)f2h(c0) | ((unsigned)f2h(c1) << 16);  // V pair ch0,ch0+1
          o.z = (unsigned)f2h(a2) | ((unsigned)f2h(a3) << 16);  // K pair ch0+2,+3
          o.w = (unsigned)f2h(c2) | ((unsigned)f2h(c3) << 16);  // V pair ch0+2,+3
          *(uint4*)((unsigned*)kvb + (size_t)gr * 128 + ch0) = o;
        }
      }
    }
  }
}

// ---------------- fused attention + beta gate + LN + GELU ----------------
// Edge loop: 4 edge-groups x 16 lanes (lane u owns ch 8u..8u+7, 32B/row);
// exp/mask/d amortized over 4 edges. Then an in-wave LDS transpose hands each
// lane channels 2l,2l+1 for the cheap 2-erff epilogue (R14 layout).
__global__ __launch_bounds__(256, 8) void attn_fused(
    const unsigned short* __restrict__ qb, const unsigned* __restrict__ kvu,
    const unsigned short* __restrict__ sb, const int* __restrict__ starts,
    const int* __restrict__ csr, const float* __restrict__ Wbeta,
    const float* __restrict__ lng, const float* __restrict__ lnb,
    unsigned short* __restrict__ hout, int N) {
  __shared__ float xS[4][HIDD];
  int wid = (blockIdx.x * 256 + threadIdx.x) >> 6;
  if (wid >= N) return;
  const int l = threadIdx.x & 63;
  const int u = l & 15;    // channel slot: ch 8u..8u+7
  const int eg = l >> 4;   // edge group 0..3
  const int wib = threadIdx.x >> 6;  // wave in block
  uint4 qw = *(const uint4*)((const unsigned*)qb + (size_t)wid * 64 + 4 * u);
  hf2 q0 = u2h2(qw.x), q1 = u2h2(qw.y), q2 = u2h2(qw.z), q3 = u2h2(qw.w);
  int s0 = starts[wid], s1 = starts[wid + 1];
  float d = 0.f;
  float o0 = 0.f, o1 = 0.f, o2 = 0.f, o3 = 0.f;
  float o4 = 0.f, o5 = 0.f, o6 = 0.f, o7 = 0.f;

#define EDGE(AA, BB, VALID)                                                    \
  {                                                                            \
    float dt = dot2a(u2h2(AA.x), q0,                                           \
               dot2a(u2h2(AA.z), q1,                                           \
               dot2a(u2h2(BB.x), q2,                                           \
               dot2a(u2h2(BB.z), q3, 0.f))));                                  \
    dt += __shfl_xor(dt, 1);                                                   \
    dt += __shfl_xor(dt, 2);                                                   \
    float p = __expf(dt);                                                      \
    if (!(VALID)) p = 0.f;                                                     \
    d += p;                                                                    \
    float2 vf;                                                                 \
    vf = __half22float2(*(__half2*)&AA.y);                                     \
    o0 = fmaf(p, vf.x, o0); o1 = fmaf(p, vf.y, o1);                            \
    vf = __half22float2(*(__half2*)&AA.w);                                     \
    o2 = fmaf(p, vf.x, o2); o3 = fmaf(p, vf.y, o3);                            \
    vf = __half22float2(*(__half2*)&BB.y);                                     \
    o4 = fmaf(p, vf.x, o4); o5 = fmaf(p, vf.y, o5);                            \
    vf = __half22float2(*(__half2*)&BB.w);                                     \
    o6 = fmaf(p, vf.x, o6); o7 = fmaf(p, vf.y, o7);                            \
  }

  int i = s0;
  for (; i + 8 <= s1; i += 8) {  // full batches: 2 edges/group, unmasked
    int src0 = csr[i + eg];
    int src1 = csr[i + 4 + eg];
    const char* r0 = (const char*)kvu + ((size_t)src0 << 9) + u * 32;
    const char* r1 = (const char*)kvu + ((size_t)src1 << 9) + u * 32;
    uint4 A0 = *(const uint4*)r0;
    uint4 B0 = *(const uint4*)(r0 + 16);
    uint4 A1 = *(const uint4*)r1;
    uint4 B1 = *(const uint4*)(r1 + 16);
    EDGE(A0, B0, true);
    EDGE(A1, B1, true);
  }
  for (; i < s1; i += 4) {  // masked tail: 1 edge/group
    int idx = i + eg;
    bool ok = idx < s1;
    int src = csr[ok ? idx : s0];
    const char* r = (const char*)kvu + ((size_t)src << 9) + u * 32;
    uint4 A = *(const uint4*)r;
    uint4 B = *(const uint4*)(r + 16);
    EDGE(A, B, ok);
  }
#undef EDGE

  // combine the 4 edge-groups
  d += __shfl_xor(d, 16); d += __shfl_xor(d, 32);
  o0 += __shfl_xor(o0, 16); o0 += __shfl_xor(o0, 32);
  o1 += __shfl_xor(o1, 16); o1 += __shfl_xor(o1, 32);
  o2 += __shfl_xor(o2, 16); o2 += __shfl_xor(o2, 32);
  o3 += __shfl_xor(o3, 16); o3 += __shfl_xor(o3, 32);
  o4 += __shfl_xor(o4, 16); o4 += __shfl_xor(o4, 32);
  o5 += __shfl_xor(o5, 16); o5 += __shfl_xor(o5, 32);
  o6 += __shfl_xor(o6, 16); o6 += __shfl_xor(o6, 32);
  o7 += __shfl_xor(o7, 16); o7 += __shfl_xor(o7, 32);
  float inv = d > 0.f ? 1.f / d : 0.f;
  o0 *= inv; o1 *= inv; o2 *= inv; o3 *= inv;
  o4 *= inv; o5 *= inv; o6 *= inv; o7 *= inv;

  // in-wave transpose: eg0 lanes publish the 128 channels; each lane reads 2.
  if (eg == 0) {
    f32x4 t0 = {o0, o1, o2, o3};
    f32x4 t1 = {o4, o5, o6, o7};
    *(f32x4*)&xS[wib][u * 8] = t0;
    *(f32x4*)&xS[wib][u * 8 + 4] = t1;
  }
  float2 oo = *(const float2*)&xS[wib][2 * l];  // same-wave LDS: waitcnt only
  float a0 = oo.x, a1 = oo.y;

  // 2-channel epilogue (ch 2l, 2l+1)
  unsigned su = ((const unsigned*)sb)[(size_t)wid * 64 + l];
  float sx = bfl((unsigned short)su), sy = bfl((unsigned short)(su >> 16));
  float2 wbo = *(const float2*)&Wbeta[2 * l];
  float2 wbx = *(const float2*)&Wbeta[128 + 2 * l];
  float2 wbd = *(const float2*)&Wbeta[256 + 2 * l];
  float bl = a0 * wbo.x + a1 * wbo.y + sx * wbx.x + sy * wbx.y
           + (a0 - sx) * wbd.x + (a1 - sy) * wbd.y;
  bl += __shfl_xor(bl, 1);  bl += __shfl_xor(bl, 2);  bl += __shfl_xor(bl, 4);
  bl += __shfl_xor(bl, 8);  bl += __shfl_xor(bl, 16); bl += __shfl_xor(bl, 32);
  float beta = 1.f / (1.f + __expf(-bl));
  float hx = beta * sx + (1.f - beta) * a0;
  float hy = beta * sy + (1.f - beta) * a1;
  float s = hx + hy, sq = hx * hx + hy * hy;
  s += __shfl_xor(s, 1);  sq += __shfl_xor(sq, 1);
  s += __shfl_xor(s, 2);  sq += __shfl_xor(sq, 2);
  s += __shfl_xor(s, 4);  sq += __shfl_xor(sq, 4);
  s += __shfl_xor(s, 8);  sq += __shfl_xor(sq, 8);
  s += __shfl_xor(s, 16); sq += __shfl_xor(sq, 16);
  s += __shfl_xor(s, 32); sq += __shfl_xor(sq, 32);
  float mu = s * (1.f / 128.f);
  float var = sq * (1.f / 128.f) - mu * mu;
  float rstd = 1.f / sqrtf(var + 1e-5f);
  float2 g2 = *(const float2*)&lng[2 * l];
  float2 b2 = *(const float2*)&lnb[2 * l];
  float y0 = (hx - mu) * rstd * g2.x + b2.x;
  float y1 = (hy - mu) * rstd * g2.y + b2.y;
  y0 = 0.5f * y0 * (1.f + erff(y0 * 0.70710678118654752f));
  y1 = 0.5f * y1 * (1.f + erff(y1 * 0.70710678118654752f));
  unsigned outw = (unsigned)f2bf(y0) | ((unsigned)f2bf(y1) << 16);
  ((unsigned*)hout)[(size_t)wid * 64 + l] = outw;
}

// ---------------- fused mean-pool + MLP: one block per graph ----------------
__global__ __launch_bounds__(1024) void pool_mlp_kernel(
    const unsigned short* __restrict__ h, const int* __restrict__ batch,
    const float* __restrict__ W1, const float* __restrict__ b1,
    const float* __restrict__ W2, const float* __restrict__ b2,
    float* __restrict__ out, int N) {
  __shared__ float accS[16][HIDD];
  __shared__ float gS[HIDD];
  __shared__ float red[2];
  const int g = blockIdx.x, t = threadIdx.x;
  int lo, hi;
  {
    int a = 0, b = N;
    while (a < b) { int m = (a + b) >> 1; if (batch[m] < g) a = m + 1; else b = m; }
    lo = a;
    b = N;
    while (a < b) { int m = (a + b) >> 1; if (batch[m] < g + 1) a = m + 1; else b = m; }
    hi = a;
  }
  const unsigned* h32 = (const unsigned*)h;
  const int rg = t >> 6, u = t & 63;  // 16 row-groups x 64 lanes
  float a0 = 0.f, a1 = 0.f;
  int n = lo + rg;
  for (; n + 48 < hi; n += 64) {  // 4 independent loads in flight
    unsigned w0 = h32[(size_t)n * 64 + u];
    unsigned w1 = h32[(size_t)(n + 16) * 64 + u];
    unsigned w2 = h32[(size_t)(n + 32) * 64 + u];
    unsigned w3 = h32[(size_t)(n + 48) * 64 + u];
    a0 += bfl((unsigned short)w0) + bfl((unsigned short)w1)
        + bfl((unsigned short)w2) + bfl((unsigned short)w3);
    a1 += bfl((unsigned short)(w0 >> 16)) + bfl((unsigned short)(w1 >> 16))
        + bfl((unsigned short)(w2 >> 16)) + bfl((unsigned short)(w3 >> 16));
  }
  for (; n < hi; n += 16) {
    unsigned w = h32[(size_t)n * 64 + u];
    a0 += bfl((unsigned short)w);
    a1 += bfl((unsigned short)(w >> 16));
  }
  accS[rg][2 * u] = a0;
  accS[rg][2 * u + 1] = a1;
  __syncthreads();
  if (t < HIDD) {
    float s = 0.f;
#pragma unroll
    for (int r = 0; r < 16; ++r) s += accS[r][t];
    gS[t] = s / fmaxf((float)(hi - lo), 1.f);
  }
  __syncthreads();
  if (t < HIDD) {
    float s = b1[t];
#pragma unroll 4
    for (int k = 0; k < HIDD; ++k) s = fmaf(gS[k], W1[k * HIDD + t], s);
    s = 0.5f * s * (1.f + erff(s * 0.70710678118654752f));
    float p = s * W2[t];
    p += __shfl_xor(p, 1);  p += __shfl_xor(p, 2);  p += __shfl_xor(p, 4);
    p += __shfl_xor(p, 8);  p += __shfl_xor(p, 16); p += __shfl_xor(p, 32);
    if ((t & 63) == 0) red[t >> 6] = p;
  }
  __syncthreads();
  if (t == 0) out[g] = red[0] + red[1] + b2[0];
}

extern "C" void kernel_launch(void* const* d_in, const int* in_sizes, int n_in,
                              void* d_out, int out_size, void* d_ws, size_t ws_size,
                              hipStream_t stream) {
  const float* x        = (const float*)d_in[0];
  const int*   ei       = (const int*)d_in[1];
  const int*   batch    = (const int*)d_in[2];
  const float* l0_Wq    = (const float*)d_in[3];
  const float* l0_bq    = (const float*)d_in[4];
  const float* l0_Wk    = (const float*)d_in[5];
  const float* l0_bk    = (const float*)d_in[6];
  const float* l0_Wv    = (const float*)d_in[7];
  const float* l0_bv    = (const float*)d_in[8];
  const float* l0_Ws    = (const float*)d_in[9];
  const float* l0_bs    = (const float*)d_in[10];
  const float* l0_Wbeta = (const float*)d_in[11];
  const float* l0_lng   = (const float*)d_in[12];
  const float* l0_lnb   = (const float*)d_in[13];
  const float* Wq       = (const float*)d_in[14];
  const float* bq       = (const float*)d_in[15];
  const float* Wk       = (const float*)d_in[16];
  const float* bk       = (const float*)d_in[17];
  const float* Wv       = (const float*)d_in[18];
  const float* bv       = (const float*)d_in[19];
  const float* Ws       = (const float*)d_in[20];
  const float* bs       = (const float*)d_in[21];
  const float* Wbeta    = (const float*)d_in[22];
  const float* lng      = (const float*)d_in[23];
  const float* lnb      = (const float*)d_in[24];
  const float* mlp_W1   = (const float*)d_in[25];
  const float* mlp_b1   = (const float*)d_in[26];
  const float* mlp_W2   = (const float*)d_in[27];
  const float* mlp_b2   = (const float*)d_in[28];
  float* outp = (float*)d_out;

  char* ws = (char*)d_ws;
  size_t off = 0;
  auto alloc = [&](size_t bytes) -> void* {
    void* p = ws + off;
    off = (off + bytes + 255) & ~(size_t)255;
    return p;
  };
  unsigned short* h0  = (unsigned short*)alloc((size_t)NN * HIDD * 2);
  unsigned short* h1  = (unsigned short*)alloc((size_t)NN * HIDD * 2);
  unsigned short* qbv = (unsigned short*)alloc((size_t)NN * HIDD * 2);
  unsigned short* sbv = (unsigned short*)alloc((size_t)NN * HIDD * 2);
  unsigned short* kvb = (unsigned short*)alloc((size_t)NN * 256 * 2);
  short*  wT     = (short*)alloc((size_t)163840 * 2);
  int*    starts = (int*)alloc((size_t)(NN + 1) * 4);
  int*    pos    = (int*)alloc((size_t)NN * 4);
  int*    csr    = (int*)alloc((size_t)(EE + 8) * 4);
  int*    btot   = (int*)alloc((size_t)NB1 * 4);
  int*    boff   = (int*)alloc((size_t)NB1 * 4);
  (void)ws_size; (void)in_sizes; (void)n_in; (void)out_size;

  // ---- weight prep (transpose + bf16 + pre-swizzle) ----
  PrepW pw = {{l0_Wq, l0_Wk, l0_Wv, l0_Ws,
               Wq, Wk, Wv, Ws,
               Wq + 16384, Wk + 16384, Wv + 16384, Ws + 16384}};
  prep_kernel<<<640, 256, 0, stream>>>(pw, wT);

  // ---- CSR build (by dst) ----
  hipMemsetAsync(pos, 0, (size_t)NN * 4, stream);
  count_kernel<<<(EE + 255) / 256, 256, 0, stream>>>(ei, pos, EE);
  scan1_kernel<<<NB1, 1024, 0, stream>>>(pos, starts, btot);
  scan2_kernel<<<1, 64, 0, stream>>>(btot, boff, starts);
  scan3_kernel<<<(NN + 255) / 256, 256, 0, stream>>>(starts, boff, pos);
  scatter_kernel<<<(EE + 255) / 256, 256, 0, stream>>>(ei, pos, csr, EE);

  dim3 ggrid(256, 2);
  int agrid = (NN + 3) / 4;
  const unsigned* kvu = (const unsigned*)kvb;

  // ---- layer 0 (64 -> 128, f32 input; mats at wT) ----
  BiasW b0 = {{l0_bq, l0_bk, l0_bv, l0_bs}};
  gemm_pair<DIN, false><<<ggrid, 512, 0, stream>>>(x, wT, b0, qbv, kvb, sbv, NN);
  attn_fused<<<agrid, 256, 0, stream>>>(qbv, kvu, sbv, starts, csr, l0_Wbeta,
                                        l0_lng, l0_lnb, h0, NN);

  // ---- layer 1 (mats at wT+32768) ----
  BiasW b1s = {{bq, bk, bv, bs}};
  gemm_pair<HIDD, true><<<ggrid, 512, 0, stream>>>(h0, wT + 32768, b1s, qbv, kvb, sbv, NN);
  attn_fused<<<agrid, 256, 0, stream>>>(qbv, kvu, sbv, starts, csr, Wbeta,
                                        lng, lnb, h1, NN);

  // ---- layer 2 (mats at wT+98304) ----
  BiasW b2s = {{bq + HIDD, bk + HIDD, bv + HIDD, bs + HIDD}};
  gemm_pair<HIDD, true><<<ggrid, 512, 0, stream>>>(h1, wT + 98304, b2s, qbv, kvb, sbv, NN);
  attn_fused<<<agrid, 256, 0, stream>>>(qbv, kvu, sbv, starts, csr, Wbeta + 384,
                                        lng + HIDD, lnb + HIDD, h0, NN);

  // ---- fused pool + MLP ----
  pool_mlp_kernel<<<NG, 1024, 0, stream>>>(h0, batch, mlp_W1, mlp_b1, mlp_W2,
                                           mlp_b2, outp, NN);
}

// Round 17
// 301.377 us; speedup vs baseline: 2.1521x; 2.1521x over previous
//
#include <hip/hip_runtime.h>
#include <hip/hip_bf16.h>
#include <hip/hip_fp16.h>

#define NN 50000
#define EE 500000
#define DIN 64
#define HIDD 128
#define NG 64
#define NB1 49  // ceil(NN/1024) scan blocks

typedef short short8 __attribute__((ext_vector_type(8)));
typedef float f32x4 __attribute__((ext_vector_type(4)));
typedef _Float16 hf2 __attribute__((ext_vector_type(2)));

// async global->LDS, 16B per lane; LDS dest = wave-uniform base + lane*16
#define GLL(g, l)                                                              \
  __builtin_amdgcn_global_load_lds(                                            \
      (const __attribute__((address_space(1))) unsigned*)(g),                  \
      (__attribute__((address_space(3))) unsigned*)(l), 16, 0, 0)

__device__ __forceinline__ unsigned short f2bf(float f) {
  unsigned u = __float_as_uint(f);
  u += 0x7fffu + ((u >> 16) & 1u);  // RNE
  return (unsigned short)(u >> 16);
}
__device__ __forceinline__ float bfl(unsigned short u) {
  return __uint_as_float((unsigned)u << 16);
}
__device__ __forceinline__ unsigned short f2h(float f) {
  __half h = __float2half(f);
  return *(unsigned short*)&h;
}
__device__ __forceinline__ hf2 u2h2(unsigned u) {
  union { unsigned u; hf2 h; } c; c.u = u; return c.h;
}
__device__ __forceinline__ float dot2a(hf2 a, hf2 b, float c) {
#if __has_builtin(__builtin_amdgcn_fdot2)
  return __builtin_amdgcn_fdot2(a, b, c, false);
#else
  return c + (float)a.x * (float)b.x + (float)a.y * (float)b.y;
#endif
}

struct BiasW { const float* b[4]; };
struct PrepW { const float* w[12]; };

// ---------------- CSR build ----------------
__global__ __launch_bounds__(256) void count_kernel(const int* __restrict__ ei,
                                                    int* __restrict__ cnt, int E) {
  int e = blockIdx.x * 256 + threadIdx.x;
  if (e < E) atomicAdd(&cnt[ei[E + e]], 1);
}

__global__ __launch_bounds__(1024) void scan1_kernel(const int* __restrict__ cnts,
                                                     int* __restrict__ starts,
                                                     int* __restrict__ btot) {
  __shared__ int sh[1024];
  int t = threadIdx.x;
  int idx = blockIdx.x * 1024 + t;
  int v = (idx < NN) ? cnts[idx] : 0;
  sh[t] = v;
  __syncthreads();
  for (int off = 1; off < 1024; off <<= 1) {
    int add = (t >= off) ? sh[t - off] : 0;
    __syncthreads();
    sh[t] += add;
    __syncthreads();
  }
  if (idx < NN) starts[idx] = sh[t] - v;
  if (t == 1023) btot[blockIdx.x] = sh[1023];
}

__global__ __launch_bounds__(64) void scan2_kernel(const int* __restrict__ btot,
                                                   int* __restrict__ boff,
                                                   int* __restrict__ starts) {
  int t = threadIdx.x;
  int orig = (t < NB1) ? btot[t] : 0;
  int v = orig;
  for (int off = 1; off < 64; off <<= 1) {
    int n_ = __shfl_up(v, off);
    if (t >= off) v += n_;
  }
  if (t < NB1) boff[t] = v - orig;
  if (t == NB1 - 1) starts[NN] = v;
}

__global__ __launch_bounds__(256) void scan3_kernel(int* __restrict__ starts,
                                                    const int* __restrict__ boff,
                                                    int* __restrict__ pos) {
  int i = blockIdx.x * 256 + threadIdx.x;
  if (i < NN) {
    int s = starts[i] + boff[i >> 10];
    starts[i] = s;
    pos[i] = s;
  }
}

__global__ __launch_bounds__(256) void scatter_kernel(const int* __restrict__ ei,
                                                      int* __restrict__ pos,
                                                      int* __restrict__ csr_src, int E) {
  int e = blockIdx.x * 256 + threadIdx.x;
  if (e < 8) csr_src[E + e] = 0;  // zero pad so tail batches can overread safely
  if (e < E) {
    int dst = ei[E + e];
    int p = atomicAdd(&pos[dst], 1);
    csr_src[p] = ei[e];
  }
}

// ---------------- weight prep: transpose + bf16 + PRE-SWIZZLE ----------------
// Stored so a LINEAR global_load_lds copy yields the XOR-swizzled LDS image:
//   LDSbyte[col*RB + (slot*16 ^ ((col&7)<<4)) + 2j] = W[slot*8+j][col]
// mats 0..3 (l0, K=64): at m*8192 shorts; mats 4..11 (K=128): at 32768+(m-4)*16384
__global__ __launch_bounds__(256) void prep_kernel(PrepW pw, short* __restrict__ wT) {
  int o = blockIdx.x * 256 + threadIdx.x;
  if (o >= 163840) return;
  int m, local, K;
  if (o < 32768) { m = o >> 13; local = o & 8191; K = 64; }
  else { int oo = o - 32768; m = 4 + (oo >> 14); local = oo & 16383; K = 128; }
  int col = local / K;
  int off = (local % K) * 2;              // byte offset within col
  int sw = off ^ ((col & 7) << 4);        // un-swizzle (XOR hits bits 4-6 only)
  int k = (sw >> 4) * 8 + ((sw & 15) >> 1);
  wT[o] = (short)f2bf(pw.w[m][(size_t)k * 128 + col]);
}

// ---------------- paired-mat persistent GEMM (256 threads, R13-proven) --------
// grid (GX, 2): y=0 computes Q & S, y=1 computes K & V. Both mats' B staged into
// LDS once (2x32KB), then grid-stride over 64-row chunks; A-fragments loaded once
// per chunk feed BOTH mats' MFMAs. NO launch_bounds VGPR cap (R16 spilled).
template <int K, bool BF16IN>
__global__ __launch_bounds__(256) void gemm_pair(
    const void* __restrict__ hin, const short* __restrict__ wT, BiasW bw,
    unsigned short* __restrict__ qb, unsigned short* __restrict__ kvb,
    unsigned short* __restrict__ sb, int N) {
  constexpr int RB = 2 * K;
  constexpr int CALLS = (128 * RB) / 4096;  // 8 (K=128) or 4 (K=64) per mat
  const float QSC = 0.17677669529663687f;   // 1/sqrt(32)
  __shared__ short bS[2][128 * K];
  const int grp = blockIdx.y;               // 0: Q,S   1: K,V
  const int m0 = grp ? 1 : 0;
  const int m1 = grp ? 2 : 3;
  const int t = threadIdx.x, l = t & 63, wv = t >> 6;

  {
    const char* g0 = (const char*)(wT + (size_t)m0 * 128 * K);
    const char* g1 = (const char*)(wT + (size_t)m1 * 128 * K);
    char* lp0 = (char*)&bS[0][0];
    char* lp1 = (char*)&bS[1][0];
#pragma unroll
    for (int i = 0; i < CALLS; ++i)
      GLL(g0 + i * 4096 + wv * 1024 + l * 16, lp0 + i * 4096 + wv * 1024);
#pragma unroll
    for (int i = 0; i < CALLS; ++i)
      GLL(g1 + i * 4096 + wv * 1024 + l * 16, lp1 + i * 4096 + wv * 1024);
  }
  __syncthreads();  // both B mats resident for the whole kernel

  const int lr = l & 15, lk = l >> 4;
  const float* __restrict__ bias0 = bw.b[m0];
  const float* __restrict__ bias1 = bw.b[m1];

  for (int r0 = blockIdx.x * 64 + wv * 16; r0 < N; r0 += gridDim.x * 64) {
    const int gr = r0 + lr;     // this lane's node (B-frag row AND output node)
    const bool ok = gr < N;
    short8 hfrag[K / 32];
    if (BF16IN) {
      const short* hs = (const short*)hin;
#pragma unroll
      for (int ks = 0; ks < K / 32; ++ks) {
        short8 z = {0, 0, 0, 0, 0, 0, 0, 0};
        hfrag[ks] = ok ? *(const short8*)(hs + (size_t)gr * K + ks * 32 + lk * 8) : z;
      }
    } else {
      const float* hf = (const float*)hin;
#pragma unroll
      for (int ks = 0; ks < K / 32; ++ks) {
        short8 pk = {0, 0, 0, 0, 0, 0, 0, 0};
        if (ok) {
          const float* hp = hf + (size_t)gr * K + ks * 32 + lk * 8;
          f32x4 f0 = *(const f32x4*)hp;
          f32x4 f1 = *(const f32x4*)(hp + 4);
          pk[0] = f2bf(f0.x); pk[1] = f2bf(f0.y); pk[2] = f2bf(f0.z); pk[3] = f2bf(f0.w);
          pk[4] = f2bf(f1.x); pk[5] = f2bf(f1.y); pk[6] = f2bf(f1.z); pk[7] = f2bf(f1.w);
        }
        hfrag[ks] = pk;
      }
    }

    f32x4 accA[8] = {}, accB[8] = {};
#pragma unroll
    for (int ks = 0; ks < K / 32; ++ks) {
#pragma unroll
      for (int cf = 0; cf < 8; ++cf) {
        int col = cf * 16 + lr;   // W column (channel) = A-frag row
        unsigned bb = col * RB + ((((ks * 4 + lk) * 16)) ^ ((col & 7) << 4));
        short8 w0 = *(const short8*)((const char*)&bS[0][0] + bb);
        short8 w1 = *(const short8*)((const char*)&bS[1][0] + bb);
        accA[cf] = __builtin_amdgcn_mfma_f32_16x16x32_bf16(w0, hfrag[ks], accA[cf], 0, 0, 0);
        accB[cf] = __builtin_amdgcn_mfma_f32_16x16x32_bf16(w1, hfrag[ks], accB[cf], 0, 0, 0);
      }
    }

    if (gr < N) {
#pragma unroll
      for (int cf = 0; cf < 8; ++cf) {
        int ch0 = cf * 16 + lk * 4;   // 4 contiguous channels for this lane
        f32x4 bA = *(const f32x4*)&bias0[ch0];
        f32x4 bB = *(const f32x4*)&bias1[ch0];
        float a0 = accA[cf][0] + bA.x, a1 = accA[cf][1] + bA.y;
        float a2 = accA[cf][2] + bA.z, a3 = accA[cf][3] + bA.w;
        float c0 = accB[cf][0] + bB.x, c1 = accB[cf][1] + bB.y;
        float c2 = accB[cf][2] + bB.z, c3 = accB[cf][3] + bB.w;
        if (grp == 0) {
          ushort4 q;
          q.x = f2h(a0 * QSC); q.y = f2h(a1 * QSC);
          q.z = f2h(a2 * QSC); q.w = f2h(a3 * QSC);
          *(ushort4*)&qb[(size_t)gr * 128 + ch0] = q;
          ushort4 s;
          s.x = f2bf(c0); s.y = f2bf(c1); s.z = f2bf(c2); s.w = f2bf(c3);
          *(ushort4*)&sb[(size_t)gr * 128 + ch0] = s;
        } else {
          uint4 o;
          o.x = (unsigned)f2h(a0) | ((unsigned)f2h(a1) << 16);  // K pair ch0,ch0+1
          o.y = (unsigned)f2h(c0) | ((unsigned)f2h(c1) << 16);  // V pair ch0,ch0+1
          o.z = (unsigned)f2h(a2) | ((unsigned)f2h(a3) << 16);  // K pair ch0+2,+3
          o.w = (unsigned)f2h(c2) | ((unsigned)f2h(c3) << 16);  // V pair ch0+2,+3
          *(uint4*)((unsigned*)kvb + (size_t)gr * 128 + ch0) = o;
        }
      }
    }
  }
}

// ---------------- fused attention + beta gate + LN + GELU ----------------
// Edge loop: 4 edge-groups x 16 lanes (lane u owns ch 8u..8u+7, 32B/row);
// exp/mask/d amortized over 4 edges. Then an in-wave LDS transpose hands each
// lane channels 2l,2l+1 for the cheap 2-erff epilogue (R14 layout).
__global__ __launch_bounds__(256, 8) void attn_fused(
    const unsigned short* __restrict__ qb, const unsigned* __restrict__ kvu,
    const unsigned short* __restrict__ sb, const int* __restrict__ starts,
    const int* __restrict__ csr, const float* __restrict__ Wbeta,
    const float* __restrict__ lng, const float* __restrict__ lnb,
    unsigned short* __restrict__ hout, int N) {
  __shared__ float xS[4][HIDD];
  int wid = (blockIdx.x * 256 + threadIdx.x) >> 6;
  if (wid >= N) return;
  const int l = threadIdx.x & 63;
  const int u = l & 15;    // channel slot: ch 8u..8u+7
  const int eg = l >> 4;   // edge group 0..3
  const int wib = threadIdx.x >> 6;  // wave in block
  uint4 qw = *(const uint4*)((const unsigned*)qb + (size_t)wid * 64 + 4 * u);
  hf2 q0 = u2h2(qw.x), q1 = u2h2(qw.y), q2 = u2h2(qw.z), q3 = u2h2(qw.w);
  int s0 = starts[wid], s1 = starts[wid + 1];
  float d = 0.f;
  float o0 = 0.f, o1 = 0.f, o2 = 0.f, o3 = 0.f;
  float o4 = 0.f, o5 = 0.f, o6 = 0.f, o7 = 0.f;

#define EDGE(AA, BB, VALID)                                                    \
  {                                                                            \
    float dt = dot2a(u2h2(AA.x), q0,                                           \
               dot2a(u2h2(AA.z), q1,                                           \
               dot2a(u2h2(BB.x), q2,                                           \
               dot2a(u2h2(BB.z), q3, 0.f))));                                  \
    dt += __shfl_xor(dt, 1);                                                   \
    dt += __shfl_xor(dt, 2);                                                   \
    float p = __expf(dt);                                                      \
    if (!(VALID)) p = 0.f;                                                     \
    d += p;                                                                    \
    float2 vf;                                                                 \
    vf = __half22float2(*(__half2*)&AA.y);                                     \
    o0 = fmaf(p, vf.x, o0); o1 = fmaf(p, vf.y, o1);                            \
    vf = __half22float2(*(__half2*)&AA.w);                                     \
    o2 = fmaf(p, vf.x, o2); o3 = fmaf(p, vf.y, o3);                            \
    vf = __half22float2(*(__half2*)&BB.y);                                     \
    o4 = fmaf(p, vf.x, o4); o5 = fmaf(p, vf.y, o5);                            \
    vf = __half22float2(*(__half2*)&BB.w);                                     \
    o6 = fmaf(p, vf.x, o6); o7 = fmaf(p, vf.y, o7);                            \
  }

  int i = s0;
  for (; i + 8 <= s1; i += 8) {  // full batches: 2 edges/group, unmasked
    int src0 = csr[i + eg];
    int src1 = csr[i + 4 + eg];
    const char* r0 = (const char*)kvu + ((size_t)src0 << 9) + u * 32;
    const char* r1 = (const char*)kvu + ((size_t)src1 << 9) + u * 32;
    uint4 A0 = *(const uint4*)r0;
    uint4 B0 = *(const uint4*)(r0 + 16);
    uint4 A1 = *(const uint4*)r1;
    uint4 B1 = *(const uint4*)(r1 + 16);
    EDGE(A0, B0, true);
    EDGE(A1, B1, true);
  }
  for (; i < s1; i += 4) {  // masked tail: 1 edge/group
    int idx = i + eg;
    bool ok = idx < s1;
    int src = csr[ok ? idx : s0];
    const char* r = (const char*)kvu + ((size_t)src << 9) + u * 32;
    uint4 A = *(const uint4*)r;
    uint4 B = *(const uint4*)(r + 16);
    EDGE(A, B, ok);
  }
#undef EDGE

  // combine the 4 edge-groups
  d += __shfl_xor(d, 16); d += __shfl_xor(d, 32);
  o0 += __shfl_xor(o0, 16); o0 += __shfl_xor(o0, 32);
  o1 += __shfl_xor(o1, 16); o1 += __shfl_xor(o1, 32);
  o2 += __shfl_xor(o2, 16); o2 += __shfl_xor(o2, 32);
  o3 += __shfl_xor(o3, 16); o3 += __shfl_xor(o3, 32);
  o4 += __shfl_xor(o4, 16); o4 += __shfl_xor(o4, 32);
  o5 += __shfl_xor(o5, 16); o5 += __shfl_xor(o5, 32);
  o6 += __shfl_xor(o6, 16); o6 += __shfl_xor(o6, 32);
  o7 += __shfl_xor(o7, 16); o7 += __shfl_xor(o7, 32);
  float inv = d > 0.f ? 1.f / d : 0.f;
  o0 *= inv; o1 *= inv; o2 *= inv; o3 *= inv;
  o4 *= inv; o5 *= inv; o6 *= inv; o7 *= inv;

  // in-wave transpose: eg0 lanes publish the 128 channels; each lane reads 2.
  if (eg == 0) {
    f32x4 t0 = {o0, o1, o2, o3};
    f32x4 t1 = {o4, o5, o6, o7};
    *(f32x4*)&xS[wib][u * 8] = t0;
    *(f32x4*)&xS[wib][u * 8 + 4] = t1;
  }
  float2 oo = *(const float2*)&xS[wib][2 * l];  // same-wave LDS: waitcnt only
  float a0 = oo.x, a1 = oo.y;

  // 2-channel epilogue (ch 2l, 2l+1)
  unsigned su = ((const unsigned*)sb)[(size_t)wid * 64 + l];
  float sx = bfl((unsigned short)su), sy = bfl((unsigned short)(su >> 16));
  float2 wbo = *(const float2*)&Wbeta[2 * l];
  float2 wbx = *(const float2*)&Wbeta[128 + 2 * l];
  float2 wbd = *(const float2*)&Wbeta[256 + 2 * l];
  float bl = a0 * wbo.x + a1 * wbo.y + sx * wbx.x + sy * wbx.y
           + (a0 - sx) * wbd.x + (a1 - sy) * wbd.y;
  bl += __shfl_xor(bl, 1);  bl += __shfl_xor(bl, 2);  bl += __shfl_xor(bl, 4);
  bl += __shfl_xor(bl, 8);  bl += __shfl_xor(bl, 16); bl += __shfl_xor(bl, 32);
  float beta = 1.f / (1.f + __expf(-bl));
  float hx = beta * sx + (1.f - beta) * a0;
  float hy = beta * sy + (1.f - beta) * a1;
  float s = hx + hy, sq = hx * hx + hy * hy;
  s += __shfl_xor(s, 1);  sq += __shfl_xor(sq, 1);
  s += __shfl_xor(s, 2);  sq += __shfl_xor(sq, 2);
  s += __shfl_xor(s, 4);  sq += __shfl_xor(sq, 4);
  s += __shfl_xor(s, 8);  sq += __shfl_xor(sq, 8);
  s += __shfl_xor(s, 16); sq += __shfl_xor(sq, 16);
  s += __shfl_xor(s, 32); sq += __shfl_xor(sq, 32);
  float mu = s * (1.f / 128.f);
  float var = sq * (1.f / 128.f) - mu * mu;
  float rstd = 1.f / sqrtf(var + 1e-5f);
  float2 g2 = *(const float2*)&lng[2 * l];
  float2 b2 = *(const float2*)&lnb[2 * l];
  float y0 = (hx - mu) * rstd * g2.x + b2.x;
  float y1 = (hy - mu) * rstd * g2.y + b2.y;
  y0 = 0.5f * y0 * (1.f + erff(y0 * 0.70710678118654752f));
  y1 = 0.5f * y1 * (1.f + erff(y1 * 0.70710678118654752f));
  unsigned outw = (unsigned)f2bf(y0) | ((unsigned)f2bf(y1) << 16);
  ((unsigned*)hout)[(size_t)wid * 64 + l] = outw;
}

// ---------------- fused mean-pool + MLP: one block per graph ----------------
__global__ __launch_bounds__(1024) void pool_mlp_kernel(
    const unsigned short* __restrict__ h, const int* __restrict__ batch,
    const float* __restrict__ W1, const float* __restrict__ b1,
    const float* __restrict__ W2, const float* __restrict__ b2,
    float* __restrict__ out, int N) {
  __shared__ float accS[16][HIDD];
  __shared__ float gS[HIDD];
  __shared__ float red[2];
  const int g = blockIdx.x, t = threadIdx.x;
  int lo, hi;
  {
    int a = 0, b = N;
    while (a < b) { int m = (a + b) >> 1; if (batch[m] < g) a = m + 1; else b = m; }
    lo = a;
    b = N;
    while (a < b) { int m = (a + b) >> 1; if (batch[m] < g + 1) a = m + 1; else b = m; }
    hi = a;
  }
  const unsigned* h32 = (const unsigned*)h;
  const int rg = t >> 6, u = t & 63;  // 16 row-groups x 64 lanes
  float a0 = 0.f, a1 = 0.f;
  int n = lo + rg;
  for (; n + 48 < hi; n += 64) {  // 4 independent loads in flight
    unsigned w0 = h32[(size_t)n * 64 + u];
    unsigned w1 = h32[(size_t)(n + 16) * 64 + u];
    unsigned w2 = h32[(size_t)(n + 32) * 64 + u];
    unsigned w3 = h32[(size_t)(n + 48) * 64 + u];
    a0 += bfl((unsigned short)w0) + bfl((unsigned short)w1)
        + bfl((unsigned short)w2) + bfl((unsigned short)w3);
    a1 += bfl((unsigned short)(w0 >> 16)) + bfl((unsigned short)(w1 >> 16))
        + bfl((unsigned short)(w2 >> 16)) + bfl((unsigned short)(w3 >> 16));
  }
  for (; n < hi; n += 16) {
    unsigned w = h32[(size_t)n * 64 + u];
    a0 += bfl((unsigned short)w);
    a1 += bfl((unsigned short)(w >> 16));
  }
  accS[rg][2 * u] = a0;
  accS[rg][2 * u + 1] = a1;
  __syncthreads();
  if (t < HIDD) {
    float s = 0.f;
#pragma unroll
    for (int r = 0; r < 16; ++r) s += accS[r][t];
    gS[t] = s / fmaxf((float)(hi - lo), 1.f);
  }
  __syncthreads();
  if (t < HIDD) {
    float s = b1[t];
#pragma unroll 4
    for (int k = 0; k < HIDD; ++k) s = fmaf(gS[k], W1[k * HIDD + t], s);
    s = 0.5f * s * (1.f + erff(s * 0.70710678118654752f));
    float p = s * W2[t];
    p += __shfl_xor(p, 1);  p += __shfl_xor(p, 2);  p += __shfl_xor(p, 4);
    p += __shfl_xor(p, 8);  p += __shfl_xor(p, 16); p += __shfl_xor(p, 32);
    if ((t & 63) == 0) red[t >> 6] = p;
  }
  __syncthreads();
  if (t == 0) out[g] = red[0] + red[1] + b2[0];
}

extern "C" void kernel_launch(void* const* d_in, const int* in_sizes, int n_in,
                              void* d_out, int out_size, void* d_ws, size_t ws_size,
                              hipStream_t stream) {
  const float* x        = (const float*)d_in[0];
  const int*   ei       = (const int*)d_in[1];
  const int*   batch    = (const int*)d_in[2];
  const float* l0_Wq    = (const float*)d_in[3];
  const float* l0_bq    = (const float*)d_in[4];
  const float* l0_Wk    = (const float*)d_in[5];
  const float* l0_bk    = (const float*)d_in[6];
  const float* l0_Wv    = (const float*)d_in[7];
  const float* l0_bv    = (const float*)d_in[8];
  const float* l0_Ws    = (const float*)d_in[9];
  const float* l0_bs    = (const float*)d_in[10];
  const float* l0_Wbeta = (const float*)d_in[11];
  const float* l0_lng   = (const float*)d_in[12];
  const float* l0_lnb   = (const float*)d_in[13];
  const float* Wq       = (const float*)d_in[14];
  const float* bq       = (const float*)d_in[15];
  const float* Wk       = (const float*)d_in[16];
  const float* bk       = (const float*)d_in[17];
  const float* Wv       = (const float*)d_in[18];
  const float* bv       = (const float*)d_in[19];
  const float* Ws       = (const float*)d_in[20];
  const float* bs       = (const float*)d_in[21];
  const float* Wbeta    = (const float*)d_in[22];
  const float* lng      = (const float*)d_in[23];
  const float* lnb      = (const float*)d_in[24];
  const float* mlp_W1   = (const float*)d_in[25];
  const float* mlp_b1   = (const float*)d_in[26];
  const float* mlp_W2   = (const float*)d_in[27];
  const float* mlp_b2   = (const float*)d_in[28];
  float* outp = (float*)d_out;

  char* ws = (char*)d_ws;
  size_t off = 0;
  auto alloc = [&](size_t bytes) -> void* {
    void* p = ws + off;
    off = (off + bytes + 255) & ~(size_t)255;
    return p;
  };
  unsigned short* h0  = (unsigned short*)alloc((size_t)NN * HIDD * 2);
  unsigned short* h1  = (unsigned short*)alloc((size_t)NN * HIDD * 2);
  unsigned short* qbv = (unsigned short*)alloc((size_t)NN * HIDD * 2);
  unsigned short* sbv = (unsigned short*)alloc((size_t)NN * HIDD * 2);
  unsigned short* kvb = (unsigned short*)alloc((size_t)NN * 256 * 2);
  short*  wT     = (short*)alloc((size_t)163840 * 2);
  int*    starts = (int*)alloc((size_t)(NN + 1) * 4);
  int*    pos    = (int*)alloc((size_t)NN * 4);
  int*    csr    = (int*)alloc((size_t)(EE + 8) * 4);
  int*    btot   = (int*)alloc((size_t)NB1 * 4);
  int*    boff   = (int*)alloc((size_t)NB1 * 4);
  (void)ws_size; (void)in_sizes; (void)n_in; (void)out_size;

  // ---- weight prep (transpose + bf16 + pre-swizzle) ----
  PrepW pw = {{l0_Wq, l0_Wk, l0_Wv, l0_Ws,
               Wq, Wk, Wv, Ws,
               Wq + 16384, Wk + 16384, Wv + 16384, Ws + 16384}};
  prep_kernel<<<640, 256, 0, stream>>>(pw, wT);

  // ---- CSR build (by dst) ----
  hipMemsetAsync(pos, 0, (size_t)NN * 4, stream);
  count_kernel<<<(EE + 255) / 256, 256, 0, stream>>>(ei, pos, EE);
  scan1_kernel<<<NB1, 1024, 0, stream>>>(pos, starts, btot);
  scan2_kernel<<<1, 64, 0, stream>>>(btot, boff, starts);
  scan3_kernel<<<(NN + 255) / 256, 256, 0, stream>>>(starts, boff, pos);
  scatter_kernel<<<(EE + 255) / 256, 256, 0, stream>>>(ei, pos, csr, EE);

  dim3 ggrid(256, 2);
  int agrid = (NN + 3) / 4;
  const unsigned* kvu = (const unsigned*)kvb;

  // ---- layer 0 (64 -> 128, f32 input; mats at wT) ----
  BiasW b0 = {{l0_bq, l0_bk, l0_bv, l0_bs}};
  gemm_pair<DIN, false><<<ggrid, 256, 0, stream>>>(x, wT, b0, qbv, kvb, sbv, NN);
  attn_fused<<<agrid, 256, 0, stream>>>(qbv, kvu, sbv, starts, csr, l0_Wbeta,
                                        l0_lng, l0_lnb, h0, NN);

  // ---- layer 1 (mats at wT+32768) ----
  BiasW b1s = {{bq, bk, bv, bs}};
  gemm_pair<HIDD, true><<<ggrid, 256, 0, stream>>>(h0, wT + 32768, b1s, qbv, kvb, sbv, NN);
  attn_fused<<<agrid, 256, 0, stream>>>(qbv, kvu, sbv, starts, csr, Wbeta,
                                        lng, lnb, h1, NN);

  // ---- layer 2 (mats at wT+98304) ----
  BiasW b2s = {{bq + HIDD, bk + HIDD, bv + HIDD, bs + HIDD}};
  gemm_pair<HIDD, true><<<ggrid, 256, 0, stream>>>(h1, wT + 98304, b2s, qbv, kvb, sbv, NN);
  attn_fused<<<agrid, 256, 0, stream>>>(qbv, kvu, sbv, starts, csr, Wbeta + 384,
                                        lng + HIDD, lnb + HIDD, h0, NN);

  // ---- fused pool + MLP ----
  pool_mlp_kernel<<<NG, 1024, 0, stream>>>(h0, batch, mlp_W1, mlp_b1, mlp_W2,
                                           mlp_b2, outp, NN);
}